// Round 12
// baseline (181.896 us; speedup 1.0000x reference)
//
#include <hip/hip_runtime.h>

typedef __bf16 bf16x8 __attribute__((ext_vector_type(8)));
typedef float f32x4 __attribute__((ext_vector_type(4)));
typedef float f32x2 __attribute__((ext_vector_type(2)));
typedef __fp16 fp16x2 __attribute__((ext_vector_type(2)));
typedef unsigned short ushort8 __attribute__((ext_vector_type(8)));
typedef unsigned int uint4v __attribute__((ext_vector_type(4)));
typedef unsigned int uint2v __attribute__((ext_vector_type(2)));

__device__ __forceinline__ unsigned short f2bf(float f){
    unsigned u = __float_as_uint(f);
    u += 0x7fffu + ((u >> 16) & 1u);          // RNE
    return (unsigned short)(u >> 16);
}
__device__ __forceinline__ unsigned cvt_pk_bf16(float lo, float hi){
    unsigned r;
    asm("v_cvt_pk_bf16_f32 %0, %1, %2" : "=v"(r) : "v"(lo), "v"(hi));
    return r;
}
__device__ __forceinline__ unsigned cvt_pk_f16(float lo, float hi){
    return __builtin_bit_cast(unsigned, __builtin_amdgcn_cvt_pkrtz(lo, hi));
}
__device__ __forceinline__ float fdot2(unsigned a, unsigned b, float c){
#if __has_builtin(__builtin_amdgcn_fdot2)
    return __builtin_amdgcn_fdot2(__builtin_bit_cast(fp16x2, a),
                                  __builtin_bit_cast(fp16x2, b), c, false);
#else
    float d;
    asm("v_dot2_f32_f16 %0, %1, %2, %3" : "=v"(d) : "v"(a), "v"(b), "v"(c));
    return d;
#endif
}
__device__ __forceinline__ float bflo(unsigned w){ return __uint_as_float(w << 16); }
__device__ __forceinline__ float bfhi(unsigned w){ return __uint_as_float(w & 0xffff0000u); }

// gelu via quartic Phi(x) = 0.5 + x*H(x^2), clamped to [0,1]; NO transcendentals.
__device__ __forceinline__ float gelu_poly(float x){
    float t = x * x;
    float h = fmaf(fmaf(fmaf(fmaf(2.66044e-5f, t, -7.46798e-4f), t,
                             9.014181e-3f), t, -6.5889388e-2f), t, 0.39894228f);
    float p = fmaf(x, h, 0.5f);
    p = fminf(fmaxf(p, 0.0f), 1.0f);          // folds to v_med3_f32
    return x * p;
}

#define TM 64
#define LST 136   // shorts per LDS row: 272 B, 16B-aligned

// Pack Wk/Wq/Wv (fp32 [128][128], row=k_in, col=n_out) into bf16 MFMA B-fragment
// lane order: frag b=(p*4+ks)*8+nf, lane l holds W[ks*32+(l>>4)*8+j][nf*16+(l&15)].
__global__ void pack_w_kernel(const float* __restrict__ Wk, const float* __restrict__ Wq,
                              const float* __restrict__ Wv, unsigned short* __restrict__ wp){
    int b = blockIdx.x;      // 0..95
    int lane = threadIdx.x;  // 0..63
    int p  = b >> 5;
    int ks = (b >> 3) & 3;
    int nf = b & 7;
    const float* W = (p == 0) ? Wk : ((p == 1) ? Wq : Wv);
    int k0  = ks * 32 + (lane >> 4) * 8;
    int col = nf * 16 + (lane & 15);
    unsigned short* dst = wp + ((size_t)b * 64 + lane) * 8;
    #pragma unroll
    for (int j = 0; j < 8; ++j) dst[j] = f2bf(W[(size_t)(k0 + j) * 128 + col]);
}

__global__ __launch_bounds__(256, 3) void fused_tcross(
        const float* __restrict__ x, const unsigned short* __restrict__ wp,
        const float* __restrict__ bk, const float* __restrict__ bq,
        const float* __restrict__ bv, float* __restrict__ out){
    // plane0: x bf16 (staging; A-frags hoisted to regs) -> k bf16 (written after barrier)
    // plane1: q bf16 ; plane2: v f16. After proj barrier: einsum/overlay/out are
    // wave-private (wave w owns rows [16w,16w+16)) -> no further barriers.
    __shared__ __align__(16) unsigned short smem[3 * TM * LST];   // 52224 B -> 3 blk/CU

    const int tid  = threadIdx.x;
    const int lane = tid & 63;
    const int wave = tid >> 6;
    const int c16  = lane & 15;
    const int kg   = lane >> 4;
    const long long row0 = (long long)blockIdx.x * TM;

    // bias prefetch: pi 0->v, 1->q, 2->k ; value at col (wave*2+j)*16 + c16
    float bpre0[2], bpre1[2], bpre2[2];
    #pragma unroll
    for (int j = 0; j < 2; ++j){
        int col = (wave * 2 + j) * 16 + c16;
        bpre0[j] = bv[col];
        bpre1[j] = bq[col];
        bpre2[j] = bk[col];
    }

    // ---- stage x tile (wave-private rows): fp32 -> bf16 LDS plane0; fp32 in regs ----
    const float* xblk = x + row0 * 128;
    f32x4 resid[8];
    #pragma unroll
    for (int it = 0; it < 8; ++it){
        int e = wave * 2048 + it * 256 + lane * 4;   // wave w covers rows [16w,16w+16)
        f32x4 v = *(const f32x4*)(xblk + e);
        resid[it] = v;
        uint2v w;
        w[0] = cvt_pk_bf16(v[0], v[1]);
        w[1] = cvt_pk_bf16(v[2], v[3]);
        *(uint2v*)&smem[(e >> 7) * LST + (e & 127)] = w;
    }
    __syncthreads();

    // ---- A-fragments hoisted once (reused across all 3 projections) ----
    bf16x8 af[4][4];
    #pragma unroll
    for (int m = 0; m < 4; ++m)
        #pragma unroll
        for (int ks = 0; ks < 4; ++ks)
            af[m][ks] = __builtin_bit_cast(bf16x8,
                *(const ushort8*)&smem[(m * 16 + c16) * LST + ks * 32 + kg * 8]);

    // ---- 3 projections (v,q,k; k last overwrites plane0 after barrier) ----
    const int pack_p[3] = {2, 1, 0};   // wp's p index: Wv, Wq, Wk
    #pragma unroll 1
    for (int pi = 0; pi < 3; ++pi){
        f32x4 acc[4][2];
        const f32x4 zero = {0.f, 0.f, 0.f, 0.f};
        #pragma unroll
        for (int m = 0; m < 4; ++m){ acc[m][0] = zero; acc[m][1] = zero; }
        #pragma unroll
        for (int ks = 0; ks < 4; ++ks){
            #pragma unroll
            for (int j = 0; j < 2; ++j){
                const int nf = wave * 2 + j;
                const size_t fidx = ((size_t)((pack_p[pi] * 4 + ks) * 8 + nf) * 64 + lane) * 8;
                bf16x8 wfrag = __builtin_bit_cast(bf16x8, *(const ushort8*)(wp + fidx));
                #pragma unroll
                for (int m = 0; m < 4; ++m)
                    acc[m][j] = __builtin_amdgcn_mfma_f32_16x16x32_bf16(
                        af[m][ks], wfrag, acc[m][j], 0, 0, 0);
            }
        }
        if (pi == 2) __syncthreads();  // all waves' af reads done before k hits plane0
        unsigned short* sp = smem + (2 - pi) * TM * LST;   // dest plane: v=2,q=1,k=0
        const float bb0 = (pi == 0) ? bpre0[0] : ((pi == 1) ? bpre1[0] : bpre2[0]);
        const float bb1 = (pi == 0) ? bpre0[1] : ((pi == 1) ? bpre1[1] : bpre2[1]);
        #pragma unroll
        for (int j = 0; j < 2; ++j){
            const int col = (wave * 2 + j) * 16 + c16;
            const float bb = j ? bb1 : bb0;
            #pragma unroll
            for (int m = 0; m < 4; ++m){
                float g0 = gelu_poly(acc[m][j][0] + bb);
                float g1 = gelu_poly(acc[m][j][1] + bb);
                float g2 = gelu_poly(acc[m][j][2] + bb);
                float g3 = gelu_poly(acc[m][j][3] + bb);
                // v plane f16 (dot2 operand); k/q planes bf16 (pk_fma unpack)
                unsigned u01 = (pi == 0) ? cvt_pk_f16(g0, g1) : cvt_pk_bf16(g0, g1);
                unsigned u23 = (pi == 0) ? cvt_pk_f16(g2, g3) : cvt_pk_bf16(g2, g3);
                const int r = m * 16 + kg * 4;
                sp[(r + 0) * LST + col] = (unsigned short)u01;
                sp[(r + 1) * LST + col] = (unsigned short)(u01 >> 16);
                sp[(r + 2) * LST + col] = (unsigned short)u23;
                sp[(r + 3) * LST + col] = (unsigned short)(u23 >> 16);
            }
        }
    }
    __syncthreads();   // all proj writes visible; after this, everything is wave-private

    // ---- per-row einsums: rows [16w,16w+16) per wave, 4 lanes/row ----
    const int row = tid >> 2;
    const int sub = tid & 3;
    const unsigned short* krow = smem + 0 * TM * LST + row * LST;   // bf16
    const unsigned short* qrow = smem + 1 * TM * LST + row * LST;   // bf16
    const unsigned short* vrow = smem + 2 * TM * LST + row * LST;   // f16

    f32x2 y2[8];
    #pragma unroll
    for (int e = 0; e < 8; ++e) y2[e] = (f32x2){0.f, 0.f};
    #pragma unroll
    for (int f = 0; f < 16; ++f){
        uint4v ku = *(const uint4v*)(krow + f * 8);                 // k[f][0..7]
        unsigned qw = *(const unsigned*)(qrow + f * 8 + sub * 2);   // q[f][g0..g0+1]
        f32x2 qq = {bflo(qw), bfhi(qw)};
        float kf[8] = {bflo(ku[0]), bfhi(ku[0]), bflo(ku[1]), bfhi(ku[1]),
                       bflo(ku[2]), bfhi(ku[2]), bflo(ku[3]), bfhi(ku[3])};
        #pragma unroll
        for (int e = 0; e < 8; ++e){
            f32x2 kk = {kf[e], kf[e]};
            y2[e] += kk * qq;                 // v_pk_fma_f32
        }
    }
    unsigned yp0[4], yp1[4];
    #pragma unroll
    for (int i = 0; i < 4; ++i){
        yp0[i] = cvt_pk_f16(y2[2*i][0], y2[2*i+1][0]);
        yp1[i] = cvt_pk_f16(y2[2*i][1], y2[2*i+1][1]);
    }
    f32x2 rr[16];
    #pragma unroll
    for (int f = 0; f < 16; ++f){
        uint4v vv = *(const uint4v*)(vrow + f * 8);     // v[f][e] f16 pairs over e
        float a0 = 0.f, a1 = 0.f;
        #pragma unroll
        for (int i = 0; i < 4; ++i){
            a0 = fdot2(vv[i], yp0[i], a0);
            a1 = fdot2(vv[i], yp1[i], a1);
        }
        rr[f] = (f32x2){a0, a1};                        // res[f][g0], res[f][g1]
    }

    // res overlay on own-wave rows of planes 0-1; every rr depends on all k/q reads
    // (dataflow orders reads before these writes), v-plane (plane2) never aliased.
    float* s_res = (float*)smem;   // [TM][LST] fp32 = 34816 B over planes 0-1
    #pragma unroll
    for (int f = 0; f < 16; ++f)
        *(f32x2*)&s_res[row * LST + f * 8 + sub * 2] = rr[f];

    // ---- coalesced store (wave-private rows; same-wave LDS RAW, in-order) ----
    float* outb = out + row0 * 128;
    #pragma unroll
    for (int it = 0; it < 8; ++it){
        int e = wave * 2048 + it * 256 + lane * 4;
        f32x4 rv = *(const f32x4*)&s_res[(e >> 7) * LST + (e & 127)];
        rv += resid[it];
        *(f32x4*)(outb + e) = rv;
    }
}

extern "C" void kernel_launch(void* const* d_in, const int* in_sizes, int n_in,
                              void* d_out, int out_size, void* d_ws, size_t ws_size,
                              hipStream_t stream){
    const float* x  = (const float*)d_in[0];
    const float* Wk = (const float*)d_in[1];
    const float* bk = (const float*)d_in[2];
    const float* Wq = (const float*)d_in[3];
    const float* bq = (const float*)d_in[4];
    const float* Wv = (const float*)d_in[5];
    const float* bv = (const float*)d_in[6];
    float* out = (float*)d_out;
    unsigned short* wp = (unsigned short*)d_ws;  // 96 KB of bf16 W fragments

    const int B = in_sizes[0] / 128;             // 524288, multiple of TM=64

    pack_w_kernel<<<96, 64, 0, stream>>>(Wk, Wq, Wv, wp);
    fused_tcross<<<B / TM, 256, 0, stream>>>(x, wp, bk, bq, bv, out);

    (void)n_in; (void)out_size; (void)ws_size;
}

// Round 13
// 169.254 us; speedup vs baseline: 1.0747x; 1.0747x over previous
//
#include <hip/hip_runtime.h>

typedef __bf16 bf16x8 __attribute__((ext_vector_type(8)));
typedef float f32x4 __attribute__((ext_vector_type(4)));
typedef float f32x2 __attribute__((ext_vector_type(2)));
typedef __fp16 fp16x2 __attribute__((ext_vector_type(2)));
typedef unsigned short ushort8 __attribute__((ext_vector_type(8)));
typedef unsigned int uint4v __attribute__((ext_vector_type(4)));
typedef unsigned int uint2v __attribute__((ext_vector_type(2)));

__device__ __forceinline__ unsigned short f2bf(float f){
    unsigned u = __float_as_uint(f);
    u += 0x7fffu + ((u >> 16) & 1u);          // RNE
    return (unsigned short)(u >> 16);
}
__device__ __forceinline__ unsigned cvt_pk_bf16(float lo, float hi){
    unsigned r;
    asm("v_cvt_pk_bf16_f32 %0, %1, %2" : "=v"(r) : "v"(lo), "v"(hi));
    return r;
}
__device__ __forceinline__ unsigned cvt_pk_f16(float lo, float hi){
    return __builtin_bit_cast(unsigned, __builtin_amdgcn_cvt_pkrtz(lo, hi));
}
__device__ __forceinline__ float fdot2(unsigned a, unsigned b, float c){
#if __has_builtin(__builtin_amdgcn_fdot2)
    return __builtin_amdgcn_fdot2(__builtin_bit_cast(fp16x2, a),
                                  __builtin_bit_cast(fp16x2, b), c, false);
#else
    float d;
    asm("v_dot2_f32_f16 %0, %1, %2, %3" : "=v"(d) : "v"(a), "v"(b), "v"(c));
    return d;
#endif
}
__device__ __forceinline__ float bflo(unsigned w){ return __uint_as_float(w << 16); }
__device__ __forceinline__ float bfhi(unsigned w){ return __uint_as_float(w & 0xffff0000u); }

// packed f32 math (CDNA full-rate; backend won't auto-emit from scalar code)
__device__ __forceinline__ f32x2 pk_fma2(f32x2 a, f32x2 b, f32x2 c){
    f32x2 d; asm("v_pk_fma_f32 %0, %1, %2, %3" : "=v"(d) : "v"(a), "v"(b), "v"(c)); return d;
}
__device__ __forceinline__ f32x2 pk_mul2(f32x2 a, f32x2 b){
    f32x2 d; asm("v_pk_mul_f32 %0, %1, %2" : "=v"(d) : "v"(a), "v"(b)); return d;
}
__device__ __forceinline__ f32x2 pk_add2(f32x2 a, f32x2 b){
    f32x2 d; asm("v_pk_add_f32 %0, %1, %2" : "=v"(d) : "v"(a), "v"(b)); return d;
}

#define TM 64
#define LST 136   // shorts per LDS row: 272 B, 16B-aligned

// Pack Wk/Wq/Wv (fp32 [128][128], row=k_in, col=n_out) into bf16 MFMA B-fragment
// lane order: frag b=(p*4+ks)*8+nf, lane l holds W[ks*32+(l>>4)*8+j][nf*16+(l&15)].
__global__ void pack_w_kernel(const float* __restrict__ Wk, const float* __restrict__ Wq,
                              const float* __restrict__ Wv, unsigned short* __restrict__ wp){
    int b = blockIdx.x;      // 0..95
    int lane = threadIdx.x;  // 0..63
    int p  = b >> 5;
    int ks = (b >> 3) & 3;
    int nf = b & 7;
    const float* W = (p == 0) ? Wk : ((p == 1) ? Wq : Wv);
    int k0  = ks * 32 + (lane >> 4) * 8;
    int col = nf * 16 + (lane & 15);
    unsigned short* dst = wp + ((size_t)b * 64 + lane) * 8;
    #pragma unroll
    for (int j = 0; j < 8; ++j) dst[j] = f2bf(W[(size_t)(k0 + j) * 128 + col]);
}

__global__ __launch_bounds__(256, 3) void fused_tcross(
        const float* __restrict__ x, const unsigned short* __restrict__ wp,
        const float* __restrict__ bk, const float* __restrict__ bq,
        const float* __restrict__ bv, float* __restrict__ out){
    // plane0: x bf16 (staging + A-frags) -> k bf16 (written last); plane1: q bf16;
    // plane2: v f16 (dot2 operand). After einsum: planes 0-1 reused as res fp32.
    __shared__ __align__(16) unsigned short smem[3 * TM * LST];   // 52224 B -> 3 blk/CU

    const int tid  = threadIdx.x;
    const int lane = tid & 63;
    const int wave = tid >> 6;
    const int c16  = lane & 15;
    const int kg   = lane >> 4;
    const long long row0 = (long long)blockIdx.x * TM;

    // packed-poly constants (hoisted into VGPR pairs once)
    const f32x2 C4 = {2.66044e-5f,  2.66044e-5f};
    const f32x2 C3 = {-7.46798e-4f, -7.46798e-4f};
    const f32x2 C2 = {9.014181e-3f, 9.014181e-3f};
    const f32x2 C1 = {-6.5889388e-2f, -6.5889388e-2f};
    const f32x2 C0 = {0.39894228f,  0.39894228f};
    const f32x2 CH = {0.5f, 0.5f};

    // bias prefetch: pi 0->v, 1->q, 2->k ; value at col (wave*2+j)*16 + c16
    float bpre0[2], bpre1[2], bpre2[2];
    #pragma unroll
    for (int j = 0; j < 2; ++j){
        int col = (wave * 2 + j) * 16 + c16;
        bpre0[j] = bv[col];
        bpre1[j] = bq[col];
        bpre2[j] = bk[col];
    }

    // ---- stage x tile: fp32 global -> bf16 LDS plane0; keep fp32 for residual ----
    const float* xblk = x + row0 * 128;
    f32x4 resid[8];
    #pragma unroll
    for (int it = 0; it < 8; ++it){
        int e = tid * 4 + it * 1024;               // 64*128 = 8192 elems
        f32x4 v = *(const f32x4*)(xblk + e);
        resid[it] = v;
        uint2v w;
        w[0] = cvt_pk_bf16(v[0], v[1]);
        w[1] = cvt_pk_bf16(v[2], v[3]);
        *(uint2v*)&smem[(e >> 7) * LST + (e & 127)] = w;
    }
    __syncthreads();

    // ---- 3 projections (order v,q,k so plane0/x survives until the last epilogue) ----
    const int pack_p[3] = {2, 1, 0};   // wp's p index: Wv, Wq, Wk
    const int plane[3]  = {2, 1, 0};   // dest plane:   v=2, q=1, k=0
    #pragma unroll 1
    for (int pi = 0; pi < 3; ++pi){
        f32x4 acc[4][2];
        const f32x4 zero = {0.f, 0.f, 0.f, 0.f};
        #pragma unroll
        for (int m = 0; m < 4; ++m){ acc[m][0] = zero; acc[m][1] = zero; }
        #pragma unroll
        for (int ks = 0; ks < 4; ++ks){
            bf16x8 af[4];
            #pragma unroll
            for (int m = 0; m < 4; ++m)
                af[m] = __builtin_bit_cast(bf16x8,
                    *(const ushort8*)&smem[(m * 16 + c16) * LST + ks * 32 + kg * 8]);
            #pragma unroll
            for (int j = 0; j < 2; ++j){
                const int nf = wave * 2 + j;
                const size_t fidx = ((size_t)((pack_p[pi] * 4 + ks) * 8 + nf) * 64 + lane) * 8;
                bf16x8 wfrag = __builtin_bit_cast(bf16x8, *(const ushort8*)(wp + fidx));
                #pragma unroll
                for (int m = 0; m < 4; ++m)
                    acc[m][j] = __builtin_amdgcn_mfma_f32_16x16x32_bf16(
                        af[m], wfrag, acc[m][j], 0, 0, 0);
            }
        }
        if (pi == 2) __syncthreads();  // k overwrites plane0: wait for all A-frag reads
        unsigned short* sp = smem + plane[pi] * TM * LST;
        const float bb0 = (pi == 0) ? bpre0[0] : ((pi == 1) ? bpre1[0] : bpre2[0]);
        const float bb1 = (pi == 0) ? bpre0[1] : ((pi == 1) ? bpre1[1] : bpre2[1]);
        #pragma unroll
        for (int j = 0; j < 2; ++j){
            const int col = (wave * 2 + j) * 16 + c16;
            const float bb = j ? bb1 : bb0;
            const f32x2 bb2 = {bb, bb};
            #pragma unroll
            for (int m = 0; m < 4; ++m){
                // packed bias+poly: x01/x23 pairs through v_pk_{add,mul,fma}_f32
                f32x2 x01 = pk_add2((f32x2){acc[m][j][0], acc[m][j][1]}, bb2);
                f32x2 x23 = pk_add2((f32x2){acc[m][j][2], acc[m][j][3]}, bb2);
                f32x2 t01 = pk_mul2(x01, x01);
                f32x2 t23 = pk_mul2(x23, x23);
                f32x2 h01 = pk_fma2(pk_fma2(pk_fma2(pk_fma2(C4, t01, C3), t01, C2),
                                            t01, C1), t01, C0);
                f32x2 h23 = pk_fma2(pk_fma2(pk_fma2(pk_fma2(C4, t23, C3), t23, C2),
                                            t23, C1), t23, C0);
                f32x2 p01 = pk_fma2(x01, h01, CH);
                f32x2 p23 = pk_fma2(x23, h23, CH);
                // scalar clamp (v_med3_f32) + final mul
                float g0 = x01[0] * fminf(fmaxf(p01[0], 0.0f), 1.0f);
                float g1 = x01[1] * fminf(fmaxf(p01[1], 0.0f), 1.0f);
                float g2 = x23[0] * fminf(fmaxf(p23[0], 0.0f), 1.0f);
                float g3 = x23[1] * fminf(fmaxf(p23[1], 0.0f), 1.0f);
                // v plane in f16 (dot2 operand); k/q planes in bf16 (pk_fma unpack)
                unsigned u01 = (pi == 0) ? cvt_pk_f16(g0, g1) : cvt_pk_bf16(g0, g1);
                unsigned u23 = (pi == 0) ? cvt_pk_f16(g2, g3) : cvt_pk_bf16(g2, g3);
                const int r = m * 16 + kg * 4;
                sp[(r + 0) * LST + col] = (unsigned short)u01;
                sp[(r + 1) * LST + col] = (unsigned short)(u01 >> 16);
                sp[(r + 2) * LST + col] = (unsigned short)u23;
                sp[(r + 3) * LST + col] = (unsigned short)(u23 >> 16);
            }
        }
    }
    __syncthreads();

    // ---- per-row einsums: 4 lanes/row, lane owns g = {2*sub, 2*sub+1} ----
    const int row = tid >> 2;
    const int sub = tid & 3;
    const unsigned short* krow = smem + 0 * TM * LST + row * LST;   // bf16
    const unsigned short* qrow = smem + 1 * TM * LST + row * LST;   // bf16
    const unsigned short* vrow = smem + 2 * TM * LST + row * LST;   // f16

    f32x2 y2[8];
    #pragma unroll
    for (int e = 0; e < 8; ++e) y2[e] = (f32x2){0.f, 0.f};
    #pragma unroll
    for (int f = 0; f < 16; ++f){
        uint4v ku = *(const uint4v*)(krow + f * 8);                 // k[f][0..7]
        unsigned qw = *(const unsigned*)(qrow + f * 8 + sub * 2);   // q[f][g0..g0+1]
        f32x2 qq = {bflo(qw), bfhi(qw)};
        float kf[8] = {bflo(ku[0]), bfhi(ku[0]), bflo(ku[1]), bfhi(ku[1]),
                       bflo(ku[2]), bfhi(ku[2]), bflo(ku[3]), bfhi(ku[3])};
        #pragma unroll
        for (int e = 0; e < 8; ++e){
            f32x2 kk = {kf[e], kf[e]};
            y2[e] += kk * qq;                 // v_pk_fma_f32
        }
    }
    // pack y columns to f16 pairs along e for dot2: yp0 = y[.][g0], yp1 = y[.][g1]
    unsigned yp0[4], yp1[4];
    #pragma unroll
    for (int i = 0; i < 4; ++i){
        yp0[i] = cvt_pk_f16(y2[2*i][0], y2[2*i+1][0]);
        yp1[i] = cvt_pk_f16(y2[2*i][1], y2[2*i+1][1]);
    }
    f32x2 rr[16];
    #pragma unroll
    for (int f = 0; f < 16; ++f){
        uint4v vv = *(const uint4v*)(vrow + f * 8);     // v[f][e] f16 pairs over e
        float a0 = 0.f, a1 = 0.f;
        #pragma unroll
        for (int i = 0; i < 4; ++i){
            a0 = fdot2(vv[i], yp0[i], a0);
            a1 = fdot2(vv[i], yp1[i], a1);
        }
        rr[f] = (f32x2){a0, a1};                        // res[f][g0], res[f][g1]
    }
    __syncthreads();   // all k/q/v reads done before res overlays planes 0-1

    float* s_res = (float*)smem;   // [TM][LST] fp32 = 34816 B over planes 0-1
    #pragma unroll
    for (int f = 0; f < 16; ++f)
        *(f32x2*)&s_res[row * LST + f * 8 + sub * 2] = rr[f];
    __syncthreads();

    // ---- coalesced store: out = res + x (residual from regs) ----
    float* outb = out + row0 * 128;
    #pragma unroll
    for (int it = 0; it < 8; ++it){
        int e = tid * 4 + it * 1024;
        f32x4 rv = *(const f32x4*)&s_res[(e >> 7) * LST + (e & 127)];
        rv += resid[it];
        *(f32x4*)(outb + e) = rv;
    }
}

extern "C" void kernel_launch(void* const* d_in, const int* in_sizes, int n_in,
                              void* d_out, int out_size, void* d_ws, size_t ws_size,
                              hipStream_t stream){
    const float* x  = (const float*)d_in[0];
    const float* Wk = (const float*)d_in[1];
    const float* bk = (const float*)d_in[2];
    const float* Wq = (const float*)d_in[3];
    const float* bq = (const float*)d_in[4];
    const float* Wv = (const float*)d_in[5];
    const float* bv = (const float*)d_in[6];
    float* out = (float*)d_out;
    unsigned short* wp = (unsigned short*)d_ws;  // 96 KB of bf16 W fragments

    const int B = in_sizes[0] / 128;             // 524288, multiple of TM=64

    pack_w_kernel<<<96, 64, 0, stream>>>(Wk, Wq, Wv, wp);
    fused_tcross<<<B / TM, 256, 0, stream>>>(x, wp, bk, bq, bv, out);

    (void)n_in; (void)out_size; (void)ws_size;
}